// Round 11
// baseline (845.617 us; speedup 1.0000x reference)
//
#include <hip/hip_runtime.h>

#define NEG_SLOPE 0.2f
#define BSHIFT 6                 // 64 dsts per bucket
#define BSIZE  (1 << BSHIFT)
#define CAP    2688              // mean 2048, +14 sigma
#define SRC_MASK 0x1FFFF         // 17 bits for src id (n < 131072)
#define CHUNK 1024               // edges per binA chunk

__device__ __forceinline__ float lrelu(float x) { return x >= 0.f ? x : NEG_SLOPE * x; }
__device__ __forceinline__ float bf2f(unsigned short u) {
    return __uint_as_float((unsigned)u << 16);
}
__device__ __forceinline__ unsigned short f2bf(float f) {
    unsigned u = __float_as_uint(f);
    return (unsigned short)((u + 0x7fffu + ((u >> 16) & 1u)) >> 16);  // RNE
}

// Device-scope grid barrier. Each cell is used exactly once per launch and is
// zeroed by the host-side memset. All blocks are co-resident (grid sized from
// the occupancy API), so spinning cannot deadlock.
__device__ __forceinline__ void gbar(int* cell, int nblocks) {
    __syncthreads();
    if (threadIdx.x == 0) {
        __threadfence();                      // release prior writes
        atomicAdd(cell, 1);                   // device-scope by default
        while (__hip_atomic_load(cell, __ATOMIC_RELAXED, __HIP_MEMORY_SCOPE_AGENT) < nblocks) {}
        __threadfence();                      // acquire remote writes
    }
    __syncthreads();
}

// Persistent fused kernel: P1 gemm | bar | P2 binA | bar | P3 binB | bar | P4 gather
__global__ __launch_bounds__(256) void k_all(
    const float* __restrict__ A, const float* __restrict__ W,
    const float* __restrict__ att, const float* __restrict__ bias,
    const int* __restrict__ edges,
    unsigned short* __restrict__ h16, float* __restrict__ s_i, float* __restrict__ s_j,
    int* __restrict__ bcursor, int* __restrict__ bar,
    unsigned* __restrict__ pairs, int* __restrict__ srcl,
    int* __restrict__ offs, int* __restrict__ counts,
    float* __restrict__ out, int n, int n_edges, int nb)
{
    __shared__ int smem_i[4096];              // 16 KB, reused per phase
    float* smemf = (float*)smem_i;
    int tid = threadIdx.x, lane = tid & 63, wave = tid >> 6;
    int G = (int)gridDim.x, bid = (int)blockIdx.x;

    // ---- P1: gemm (W in LDS once; A broadcast via shfl) ----
    for (int t = tid; t < 4096; t += 256) smemf[t] = W[t];
    __syncthreads();
    {
        float ai = att[lane], aj = att[64 + lane];
        for (int row = bid * 4 + wave; row < n; row += G * 4) {
            float av = A[(long)row * 64 + lane];
            float a0 = 0.f, a1 = 0.f, a2 = 0.f, a3 = 0.f;
#pragma unroll
            for (int k = 0; k < 64; k += 4) {
                a0 = fmaf(__shfl(av, k,     64), smemf[(k)     * 64 + lane], a0);
                a1 = fmaf(__shfl(av, k + 1, 64), smemf[(k + 1) * 64 + lane], a1);
                a2 = fmaf(__shfl(av, k + 2, 64), smemf[(k + 2) * 64 + lane], a2);
                a3 = fmaf(__shfl(av, k + 3, 64), smemf[(k + 3) * 64 + lane], a3);
            }
            float acc = (a0 + a1) + (a2 + a3);
            h16[(long)row * 64 + lane] = f2bf(acc);
            float vi = acc * ai, vj = acc * aj;
#pragma unroll
            for (int o = 32; o; o >>= 1) {
                vi += __shfl_xor(vi, o, 64);
                vj += __shfl_xor(vj, o, 64);
            }
            if (lane == 0) { s_i[row] = vi; s_j[row] = vj; }
        }
    }

    gbar(&bar[0], G);

    // ---- P2: binA — bucket binning, windowed pair emit ----
    {
        int* hist = smem_i;                   // nb ints (<=2048)
        int* cur  = smem_i + 2048;            // nb ints
        int nchunks = (n_edges + CHUNK - 1) / CHUNK;
        for (int c = bid; c < nchunks; c += G) {
            long base = (long)c * CHUNK;
            for (int b = tid; b < nb; b += 256) hist[b] = 0;
            __syncthreads();
#pragma unroll
            for (int k = 0; k < CHUNK / 256; ++k) {
                long e = base + k * 256 + tid;
                if (e < n_edges) {
                    int d = edges[e]; int i = (int)(e >> 5);
                    if (d != i) atomicAdd(&hist[d >> BSHIFT], 1);
                }
            }
            __syncthreads();
            for (int b = tid; b < nb; b += 256) {
                int cc = hist[b]; int g = 0;
                if (cc) g = atomicAdd(&bcursor[b], cc);
                cur[b] = b * CAP + g;
            }
            __syncthreads();
#pragma unroll
            for (int k = 0; k < CHUNK / 256; ++k) {
                long e = base + k * 256 + tid;
                if (e < n_edges) {
                    int d = edges[e]; int i = (int)(e >> 5);
                    if (d != i) {
                        int b = d >> BSHIFT;
                        int slot = atomicAdd(&cur[b], 1);
                        if (slot < (b + 1) * CAP)
                            pairs[slot] = ((unsigned)(d & (BSIZE - 1)) << 17) | (unsigned)i;
                    }
                }
            }
            __syncthreads();
        }
    }

    gbar(&bar[1], G);

    // ---- P3: binB — per-bucket hist+scan, scatter to srcl ----
    {
        int* hist = smem_i;
        int* scn  = smem_i + 64;
        int* cur  = smem_i + 128;
        for (int b = bid; b < nb; b += G) {
            int cnt = bcursor[b]; if (cnt > CAP) cnt = CAP;
            int wb = b * CAP;
            if (tid < BSIZE) hist[tid] = 0;
            __syncthreads();
            for (int s = tid; s < cnt; s += 256) atomicAdd(&hist[pairs[wb + s] >> 17], 1);
            __syncthreads();
            if (tid < BSIZE) scn[tid] = hist[tid];
            __syncthreads();
            for (int dd = 1; dd < BSIZE; dd <<= 1) {
                int v = 0;
                if (tid < BSIZE && tid >= dd) v = scn[tid - dd];
                __syncthreads();
                if (tid < BSIZE) scn[tid] += v;
                __syncthreads();
            }
            if (tid < BSIZE) {
                int start = scn[tid] - hist[tid];
                int dg = (b << BSHIFT) + tid;
                if (dg < n) {
                    offs[dg] = wb + start;
                    counts[dg] = hist[tid];
                }
                cur[tid] = start;
            }
            __syncthreads();
            for (int s = tid; s < cnt; s += 256) {
                unsigned pk = pairs[wb + s];
                int pos = atomicAdd(&cur[pk >> 17], 1);
                srcl[wb + pos] = (int)(pk & SRC_MASK);
            }
            __syncthreads();
        }
    }

    gbar(&bar[2], G);

    // ---- P4: gather (R7 inner loop), grid-stride over dst nodes ----
    for (int d = bid * 4 + wave; d < n; d += G * 4) {
        int off = offs[d], deg = counts[d];
        float si = s_i[d];
        float es = __expf(lrelu(si + s_j[d]));   // self-loop weight

        float acc = 0.f, denp = 0.f;
        for (int base = 0; base < deg; base += 64) {
            int t = base + lane;
            int cnt = min(64, deg - base);
            int s = 0; float w = 0.f;
            if (t < deg) {
                s = srcl[off + t];
                w = __expf(lrelu(si + s_j[s]));
            }
            denp += w;
            int j = 0;
            for (; j + 4 <= cnt; j += 4) {
                int   s0 = __shfl(s, j, 64),     s1 = __shfl(s, j + 1, 64);
                int   s2 = __shfl(s, j + 2, 64), s3 = __shfl(s, j + 3, 64);
                float w0 = __shfl(w, j, 64),     w1 = __shfl(w, j + 1, 64);
                float w2 = __shfl(w, j + 2, 64), w3 = __shfl(w, j + 3, 64);
                float h0 = bf2f(h16[(unsigned)(s0 << 6) | lane]);
                float h1 = bf2f(h16[(unsigned)(s1 << 6) | lane]);
                float h2 = bf2f(h16[(unsigned)(s2 << 6) | lane]);
                float h3 = bf2f(h16[(unsigned)(s3 << 6) | lane]);
                acc = fmaf(h0, w0, acc); acc = fmaf(h1, w1, acc);
                acc = fmaf(h2, w2, acc); acc = fmaf(h3, w3, acc);
            }
            for (; j < cnt; ++j) {
                int   ss = __shfl(s, j, 64);
                float ww = __shfl(w, j, 64);
                acc = fmaf(bf2f(h16[(unsigned)(ss << 6) | lane]), ww, acc);
            }
        }

#pragma unroll
        for (int o = 32; o; o >>= 1) denp += __shfl_xor(denp, o, 64);

        float hd = bf2f(h16[(unsigned)(d << 6) | lane]);
        acc = fmaf(hd, es, acc);
        float den = denp + es + 1e-16f;
        float v = acc / den + bias[lane];
        float sq = v * v;
#pragma unroll
        for (int o = 32; o; o >>= 1) sq += __shfl_xor(sq, o, 64);
        v = v / fmaxf(sqrtf(sq), 1e-12f);
        out[(long)d * 64 + lane] = v;
    }
}

extern "C" void kernel_launch(void* const* d_in, const int* in_sizes, int n_in,
                              void* d_out, int out_size, void* d_ws, size_t ws_size,
                              hipStream_t stream)
{
    const float* A    = (const float*)d_in[0]; // all_embed (n,64) f32
    const float* W    = (const float*)d_in[1]; // (64,64) f32
    const float* att  = (const float*)d_in[2]; // (128,) f32
    const float* bias = (const float*)d_in[3]; // (64,) f32
    const int* edges  = (const int*)d_in[7];   // (n,32) int32

    int n = in_sizes[0] / 64;           // 100000
    int n_edges = in_sizes[7];          // n * 32
    int nb = (n + BSIZE - 1) >> BSHIFT; // 1563 buckets

    // workspace layout (~48 MB)
    unsigned short* h16 = (unsigned short*)d_ws;      // n*64 bf16    12.8 MB
    float* s_i      = (float*)(h16 + (long)n * 64);   // n
    float* s_j      = s_i + n;                        // n
    int* offs       = (int*)(s_j + n);                // n
    int* counts     = offs + n;                       // n
    int* bcursor    = counts + n;                     // nb
    int* bar        = bcursor + nb;                   // 8
    unsigned* pairs = (unsigned*)(bar + 8);           // nb*CAP       16.8 MB
    int* srcl       = (int*)(pairs + (long)nb * CAP); // nb*CAP       16.8 MB

    // zero bucket cursors + barrier cells in one memset
    (void)hipMemsetAsync(bcursor, 0, (size_t)(nb + 8) * sizeof(int), stream);

    // size the grid so all blocks are co-resident (barrier cannot deadlock)
    int occ = 0;
    int G = 512;  // conservative fallback: 2 blocks/CU is always co-resident here
    if (hipOccupancyMaxActiveBlocksPerMultiprocessor(&occ, k_all, 256, 0) == hipSuccess
        && occ > 0) {
        long g = (long)occ * 256;       // 256 CUs on MI355X
        G = (int)(g < 2048 ? g : 2048);
    }

    k_all<<<G, 256, 0, stream>>>(A, W, att, bias, edges, h16, s_i, s_j,
                                 bcursor, bar, pairs, srcl, offs, counts,
                                 (float*)d_out, n, n_edges, nb);
}